// Round 7
// baseline (419.691 us; speedup 1.0000x reference)
//
#include <hip/hip_runtime.h>
#include <hip/hip_cooperative_groups.h>

namespace cg = cooperative_groups;

#define DD 512
#define MM 64
#define BB 16
#define NN 8192
#define KK 4
#define DP1 513
#define CAP 1024
#define NPAIR (NN * KK)
#define GRID_C 512

// ws byte offsets (shared by coop + fallback paths)
#define CNT_B  0                      // 64 int expert counts (256 B)
#define BLKC_B 256                    // int [128][64] per-block counts / offsets (32 KB)
#define BKT_B  33024                  // 64*1024 ushort pair ids (128 KB)
#define U_B    164096                 // bf16 u[m][d][b], 1 MB
#define UT_B   1212672                // bf16 ut[m][b][d], 1 MB
#define WBF_B  2261248                // bf16 w[n][d], 8 MB
#define PART_B 10649856               // bf16 part[k][n][d], 32 MB
#define WS_NEED 44204288

typedef unsigned int uint;
typedef unsigned short ushort;
typedef __attribute__((ext_vector_type(8))) short short8;
typedef __attribute__((ext_vector_type(4))) float f32x4;

__device__ __forceinline__ ushort f2bf(float f) {
    uint u = __builtin_bit_cast(uint, f);
    uint r = (u + 0x7FFFu + ((u >> 16) & 1u)) >> 16;
    return (ushort)r;
}
__device__ __forceinline__ float bf2f(ushort s) {
    return __builtin_bit_cast(float, (uint)s << 16);
}

// ===========================================================================
// Cooperative mega-kernel: prep | count || prefix | scatter | writes | reduce | recon
// ===========================================================================
__global__ __launch_bounds__(256) void fused_all(
    const float* __restrict__ h_sparse,
    const int*   __restrict__ topk,
    const float* __restrict__ U,
    void* __restrict__ ws,
    float* __restrict__ out)
{
    cg::grid_group grid = cg::this_grid();
    const int blk = blockIdx.x, t = threadIdx.x;
    const int wave = t >> 6, lane = t & 63;
    const int quad = lane >> 4, l15 = lane & 15;

    __shared__ float  s_red[256];
    __shared__ float  s_inv[16];
    __shared__ ushort s_tr[16][136];
    __shared__ int    s_cnt[128];
    __shared__ float  s_loss;

    int*    cnt    = (int*)ws;
    int*    blkc   = (int*)((char*)ws + BLKC_B);
    ushort* bkt    = (ushort*)((char*)ws + BKT_B);
    ushort* ubase  = (ushort*)((char*)ws + U_B);
    ushort* utbase = (ushort*)((char*)ws + UT_B);
    ushort* wbf    = (ushort*)((char*)ws + WBF_B);
    ushort* part   = (ushort*)((char*)ws + PART_B);

    // ---------------- P0: prep (blocks 0-255) + count (256-383) ----------------
    if (blk < 256) {
        const int m = blk >> 2, sl = blk & 3;           // expert, d-slice of 128
        const float* Um = U + (long)m * DP1 * BB;
        float a = 0.f;
        for (int i = t; i < DP1 * BB; i += 256) { float v = Um[i]; a += v * v; }
        s_red[t] = a;
        __syncthreads();
        if (t < 16) {
            float tot = 0.f;
            #pragma unroll
            for (int j = 0; j < 16; ++j) tot += s_red[t + 16 * j];
            s_inv[t] = rsqrtf(tot);
        }
        __syncthreads();
        ushort* ub = ubase + (long)m * DD * BB;
        ushort* ut = utbase + (long)m * BB * DD;
        const float* Us = Um + sl * 2048;
        #pragma unroll
        for (int iter = 0; iter < 4; ++iter) {
            const int i = t + iter * 256;               // 0..1023 elem pairs
            const int e0 = 2 * i;
            const int dl = e0 >> 4, b0 = e0 & 15;
            const float2 v = *(const float2*)(Us + e0);
            const ushort bv0 = f2bf(v.x * s_inv[b0]);
            const ushort bv1 = f2bf(v.y * s_inv[b0 + 1]);
            *(uint*)(ub + sl * 2048 + e0) = (uint)bv0 | ((uint)bv1 << 16);
            s_tr[b0][dl]     = bv0;
            s_tr[b0 + 1][dl] = bv1;
        }
        __syncthreads();
        {
            const int b = t >> 4, doff = (t & 15) * 8;
            uint4 val;
            val.x = (uint)s_tr[b][doff + 0] | ((uint)s_tr[b][doff + 1] << 16);
            val.y = (uint)s_tr[b][doff + 2] | ((uint)s_tr[b][doff + 3] << 16);
            val.z = (uint)s_tr[b][doff + 4] | ((uint)s_tr[b][doff + 5] << 16);
            val.w = (uint)s_tr[b][doff + 6] | ((uint)s_tr[b][doff + 7] << 16);
            *(uint4*)(ut + (long)b * DD + sl * 128 + doff) = val;
        }
    } else if (blk < 384) {
        const int cblk = blk - 256;
        if (t < 64) s_cnt[t] = 0;
        __syncthreads();
        const int e = topk[cblk * 256 + t];
        atomicAdd(&s_cnt[e], 1);
        __syncthreads();
        if (t < 64) blkc[cblk * 64 + t] = s_cnt[t];
    } else if (blk == 384 && t == 0) {
        out[(long)NN * DD] = 0.f;                        // loss slot
    }
    grid.sync();

    // ---------------- P1: prefix per expert (blocks 0-63) ----------------
    if (blk < 64) {
        const int e = blk;
        int orig = 0;
        if (t < 128) { orig = blkc[t * 64 + e]; s_cnt[t] = orig; }
        __syncthreads();
        #pragma unroll
        for (int off = 1; off < 128; off <<= 1) {
            int add = (t < 128 && t >= off) ? s_cnt[t - off] : 0;
            __syncthreads();
            if (t < 128) s_cnt[t] += add;
            __syncthreads();
        }
        if (t < 128) blkc[t * 64 + e] = s_cnt[t] - orig;  // exclusive offset
        if (t == 127) cnt[e] = s_cnt[127];
    }
    grid.sync();

    // ---------------- P2: scatter (blocks 256-383) ----------------
    if (blk >= 256 && blk < 384) {
        const int cblk = blk - 256;
        if (t < 64) s_cnt[t] = 0;
        __syncthreads();
        const int p = cblk * 256 + t;
        const int e = topk[p];
        const int r = atomicAdd(&s_cnt[e], 1);
        bkt[e * CAP + blkc[cblk * 64 + e] + r] = (ushort)p;
    }
    grid.sync();

    // ---------------- P3: writes (all blocks; XCD-local expert mapping) -------
    {
        const int e = blk & 63, g = blk >> 6;
        const ushort* Ue = ubase + (long)e * DD * BB;
        const int c  = cnt[e];
        const int lo = (c * g) >> 3;
        const int hi = (c * (g + 1)) >> 3;

        for (int base2 = lo + wave * 16; base2 < hi; base2 += 64) {
            const int pidx = base2 + l15;
            const bool valid = pidx < hi;
            const int id = valid ? (int)bkt[e * CAP + pidx] : 0;
            const int n = id >> 2, k = id & 3;

            short8 bfrag = (short8)0;
            if (quad < 2 && valid) {
                const float4* hp = (const float4*)(h_sparse + (long)id * BB + quad * 8);
                const float4 h0 = hp[0], h1 = hp[1];
                bfrag[0] = (short)f2bf(h0.x); bfrag[1] = (short)f2bf(h0.y);
                bfrag[2] = (short)f2bf(h0.z); bfrag[3] = (short)f2bf(h0.w);
                bfrag[4] = (short)f2bf(h1.x); bfrag[5] = (short)f2bf(h1.y);
                bfrag[6] = (short)f2bf(h1.z); bfrag[7] = (short)f2bf(h1.w);
            }
            ushort* prow = part + ((long)(k * NN + n) << 9);

            #pragma unroll 2
            for (int dt = 0; dt < 32; dt += 2) {
                short8 a0 = (short8)0, a1 = (short8)0;
                if (quad < 2) {
                    a0 = *(const short8*)(Ue + ((long)(dt * 16 + l15) << 4) + quad * 8);
                    a1 = *(const short8*)(Ue + ((long)((dt + 1) * 16 + l15) << 4) + quad * 8);
                }
                f32x4 z = {0.f, 0.f, 0.f, 0.f};
                f32x4 c0 = __builtin_amdgcn_mfma_f32_16x16x32_bf16(a0, bfrag, z, 0, 0, 0);
                f32x4 c1 = __builtin_amdgcn_mfma_f32_16x16x32_bf16(a1, bfrag, z, 0, 0, 0);

                uint p0x = (uint)f2bf(c0[0]) | ((uint)f2bf(c0[1]) << 16);
                uint p0y = (uint)f2bf(c0[2]) | ((uint)f2bf(c0[3]) << 16);
                uint p1x = (uint)f2bf(c1[0]) | ((uint)f2bf(c1[1]) << 16);
                uint p1y = (uint)f2bf(c1[2]) | ((uint)f2bf(c1[3]) << 16);
                uint q0x = __shfl_xor((int)p0x, 16, 64);
                uint q0y = __shfl_xor((int)p0y, 16, 64);
                uint q1x = __shfl_xor((int)p1x, 16, 64);
                uint q1y = __shfl_xor((int)p1y, 16, 64);

                if (valid) {
                    uint4 st;
                    int sdt;
                    if ((quad & 1) == 0) { st.x = p0x; st.y = p0y; st.z = q0x; st.w = q0y; sdt = dt; }
                    else                 { st.x = q1x; st.y = q1y; st.z = p1x; st.w = p1y; sdt = dt + 1; }
                    const int srow = (quad & 2) ? 8 : 0;
                    *(uint4*)(prow + sdt * 16 + srow) = st;
                }
            }
        }
    }
    grid.sync();

    // ---------------- P4: reduce w = sum_k part (all blocks) ----------------
    {
        const uint4* part4 = (const uint4*)part;
        uint4* wbf4 = (uint4*)wbf;
        float4* out4 = (float4*)out;
        const int gsz = NN * DD / 8;
        #pragma unroll
        for (int j = 0; j < 4; ++j) {
            const int gid = blk * 1024 + j * 256 + t;
            const uint4 v0 = part4[gid];
            const uint4 v1 = part4[(long)gsz + gid];
            const uint4 v2 = part4[2L * gsz + gid];
            const uint4 v3 = part4[3L * gsz + gid];
            float s[8];
            s[0] = bf2f((ushort)v0.x) + bf2f((ushort)v1.x) + bf2f((ushort)v2.x) + bf2f((ushort)v3.x);
            s[1] = bf2f((ushort)(v0.x >> 16)) + bf2f((ushort)(v1.x >> 16)) + bf2f((ushort)(v2.x >> 16)) + bf2f((ushort)(v3.x >> 16));
            s[2] = bf2f((ushort)v0.y) + bf2f((ushort)v1.y) + bf2f((ushort)v2.y) + bf2f((ushort)v3.y);
            s[3] = bf2f((ushort)(v0.y >> 16)) + bf2f((ushort)(v1.y >> 16)) + bf2f((ushort)(v2.y >> 16)) + bf2f((ushort)(v3.y >> 16));
            s[4] = bf2f((ushort)v0.z) + bf2f((ushort)v1.z) + bf2f((ushort)v2.z) + bf2f((ushort)v3.z);
            s[5] = bf2f((ushort)(v0.z >> 16)) + bf2f((ushort)(v1.z >> 16)) + bf2f((ushort)(v2.z >> 16)) + bf2f((ushort)(v3.z >> 16));
            s[6] = bf2f((ushort)v0.w) + bf2f((ushort)v1.w) + bf2f((ushort)v2.w) + bf2f((ushort)v3.w);
            s[7] = bf2f((ushort)(v0.w >> 16)) + bf2f((ushort)(v1.w >> 16)) + bf2f((ushort)(v2.w >> 16)) + bf2f((ushort)(v3.w >> 16));
            out4[(long)gid * 2 + 0] = make_float4(s[0], s[1], s[2], s[3]);
            out4[(long)gid * 2 + 1] = make_float4(s[4], s[5], s[6], s[7]);
            uint4 pk;
            pk.x = (uint)f2bf(s[0]) | ((uint)f2bf(s[1]) << 16);
            pk.y = (uint)f2bf(s[2]) | ((uint)f2bf(s[3]) << 16);
            pk.z = (uint)f2bf(s[4]) | ((uint)f2bf(s[5]) << 16);
            pk.w = (uint)f2bf(s[6]) | ((uint)f2bf(s[7]) << 16);
            wbf4[gid] = pk;
        }
    }
    grid.sync();

    // ---------------- P5: recon + loss (all blocks) ----------------
    {
        if (t == 0) s_loss = 0.f;
        __syncthreads();
        const int e = blk & 63, g = blk >> 6;
        const ushort* Ute = utbase + (long)e * BB * DD;
        const int c  = cnt[e];
        const int lo = (c * g) >> 3;
        const int hi = (c * (g + 1)) >> 3;

        float lsum = 0.f;
        for (int base2 = lo + wave * 16; base2 < hi; base2 += 64) {
            const int pidx = base2 + l15;
            const bool valid = pidx < hi;
            const int id = valid ? (int)bkt[e * CAP + pidx] : 0;
            const int n = id >> 2;
            const ushort* wrow = wbf + ((long)n << 9);

            f32x4 acc = {0.f, 0.f, 0.f, 0.f};
            #pragma unroll 4
            for (int kk = 0; kk < 16; ++kk) {
                const int doff = kk * 32 + quad * 8;
                const short8 afrag = *(const short8*)(wrow + doff);
                const short8 bfrag = *(const short8*)(Ute + (long)l15 * DD + doff);
                acc = __builtin_amdgcn_mfma_f32_16x16x32_bf16(afrag, bfrag, acc, 0, 0, 0);
            }
            #pragma unroll
            for (int r = 0; r < 4; ++r) {
                const int pr = base2 + quad * 4 + r;
                if (pr < hi) {
                    const int id2 = (int)bkt[e * CAP + pr];
                    const float h = h_sparse[(long)id2 * BB + l15];
                    const float d = acc[r] - h;
                    lsum += d * d;
                }
            }
        }
        #pragma unroll
        for (int off = 32; off > 0; off >>= 1) lsum += __shfl_xor(lsum, off, 64);
        if (lane == 0 && lsum != 0.f) atomicAdd(&s_loss, lsum);
        __syncthreads();
        if (t == 0 && s_loss != 0.f)
            atomicAdd(out + (long)NN * DD, s_loss * (1.0f / ((float)NN * KK * BB)));
    }
}

// ===========================================================================
// Fallback path A (R6, proven): separate kernels
// ===========================================================================
__global__ __launch_bounds__(256) void prep_kernel(
    const float* __restrict__ U, void* __restrict__ ws,
    float* __restrict__ loss_slot)
{
    const int m = blockIdx.x, t = threadIdx.x;
    const float* Um = U + (long)m * DP1 * BB;
    __shared__ float red[256];
    __shared__ float inv_s[BB];
    __shared__ ushort tr[BB][DD + 8];

    float a = 0.f;
    for (int i = t; i < DP1 * BB; i += 256) { float v = Um[i]; a += v * v; }
    red[t] = a;
    __syncthreads();
    if (t < BB) {
        float tot = 0.f;
        #pragma unroll
        for (int j = 0; j < 16; ++j) tot += red[t + 16 * j];
        inv_s[t] = rsqrtf(tot);
    }
    __syncthreads();

    ushort* ub = (ushort*)((char*)ws + U_B) + (long)m * DD * BB;
    ushort* ut = (ushort*)((char*)ws + UT_B) + (long)m * BB * DD;

    #pragma unroll
    for (int iter = 0; iter < 16; ++iter) {
        const int i = t + iter * 256;
        const int e0 = 2 * i;
        const int d = e0 >> 4, b0 = e0 & 15;
        const float2 v = *(const float2*)(Um + e0);
        const ushort bv0 = f2bf(v.x * inv_s[b0]);
        const ushort bv1 = f2bf(v.y * inv_s[b0 + 1]);
        *(uint*)(ub + e0) = (uint)bv0 | ((uint)bv1 << 16);
        tr[b0][d] = bv0;
        tr[b0 + 1][d] = bv1;
    }
    __syncthreads();
    {
        const int b = t >> 4, base = (t & 15) * 32;
        #pragma unroll
        for (int j = 0; j < 4; ++j) {
            const int doff = base + j * 8;
            uint4 val;
            val.x = (uint)tr[b][doff + 0] | ((uint)tr[b][doff + 1] << 16);
            val.y = (uint)tr[b][doff + 2] | ((uint)tr[b][doff + 3] << 16);
            val.z = (uint)tr[b][doff + 4] | ((uint)tr[b][doff + 5] << 16);
            val.w = (uint)tr[b][doff + 6] | ((uint)tr[b][doff + 7] << 16);
            *(uint4*)(ut + (long)b * DD + doff) = val;
        }
    }
    if (m == 0) {
        if (t == 0) *loss_slot = 0.f;
        if (t < 64) ((int*)ws)[t] = 0;   // zero expert counters (prep precedes build)
    }
}

__global__ __launch_bounds__(256) void build_buckets(
    const int* __restrict__ topk, void* __restrict__ ws)
{
    int* cnt = (int*)ws;
    ushort* bkt = (ushort*)((char*)ws + BKT_B);
    __shared__ int lc[MM], lb[MM];
    const int t = threadIdx.x;
    if (t < MM) lc[t] = 0;
    __syncthreads();
    const int p = blockIdx.x * 256 + t;
    const int e = topk[p];
    const int my = atomicAdd(&lc[e], 1);
    __syncthreads();
    if (t < MM) lb[t] = atomicAdd(&cnt[t], lc[t]);
    __syncthreads();
    bkt[e * CAP + lb[e] + my] = (ushort)p;
}

__global__ __launch_bounds__(256) void pass_writes_mfma(
    const float* __restrict__ h_sparse, void* __restrict__ ws)
{
    const int e = blockIdx.x & 63, g = blockIdx.x >> 6;
    const int wave = threadIdx.x >> 6, lane = threadIdx.x & 63;
    const int quad = lane >> 4, l15 = lane & 15;

    const int* cnt = (const int*)ws;
    const ushort* bkt = (const ushort*)((const char*)ws + BKT_B);
    const ushort* Ue = (const ushort*)((const char*)ws + U_B) + (long)e * DD * BB;
    ushort* part = (ushort*)((char*)ws + PART_B);

    const int c  = cnt[e];
    const int lo = (c * g) >> 3;
    const int hi = (c * (g + 1)) >> 3;

    for (int base = lo + wave * 16; base < hi; base += 64) {
        const int pidx = base + l15;
        const bool valid = pidx < hi;
        const int id = valid ? (int)bkt[e * CAP + pidx] : 0;
        const int n = id >> 2, k = id & 3;

        short8 bfrag = (short8)0;
        if (quad < 2 && valid) {
            const float4* hp = (const float4*)(h_sparse + (long)id * BB + quad * 8);
            const float4 h0 = hp[0], h1 = hp[1];
            bfrag[0] = (short)f2bf(h0.x); bfrag[1] = (short)f2bf(h0.y);
            bfrag[2] = (short)f2bf(h0.z); bfrag[3] = (short)f2bf(h0.w);
            bfrag[4] = (short)f2bf(h1.x); bfrag[5] = (short)f2bf(h1.y);
            bfrag[6] = (short)f2bf(h1.z); bfrag[7] = (short)f2bf(h1.w);
        }
        ushort* prow = part + ((long)(k * NN + n) << 9);

        #pragma unroll 2
        for (int dt = 0; dt < 32; dt += 2) {
            short8 a0 = (short8)0, a1 = (short8)0;
            if (quad < 2) {
                a0 = *(const short8*)(Ue + ((long)(dt * 16 + l15) << 4) + quad * 8);
                a1 = *(const short8*)(Ue + ((long)((dt + 1) * 16 + l15) << 4) + quad * 8);
            }
            f32x4 z = {0.f, 0.f, 0.f, 0.f};
            f32x4 c0 = __builtin_amdgcn_mfma_f32_16x16x32_bf16(a0, bfrag, z, 0, 0, 0);
            f32x4 c1 = __builtin_amdgcn_mfma_f32_16x16x32_bf16(a1, bfrag, z, 0, 0, 0);

            uint p0x = (uint)f2bf(c0[0]) | ((uint)f2bf(c0[1]) << 16);
            uint p0y = (uint)f2bf(c0[2]) | ((uint)f2bf(c0[3]) << 16);
            uint p1x = (uint)f2bf(c1[0]) | ((uint)f2bf(c1[1]) << 16);
            uint p1y = (uint)f2bf(c1[2]) | ((uint)f2bf(c1[3]) << 16);
            uint q0x = __shfl_xor((int)p0x, 16, 64);
            uint q0y = __shfl_xor((int)p0y, 16, 64);
            uint q1x = __shfl_xor((int)p1x, 16, 64);
            uint q1y = __shfl_xor((int)p1y, 16, 64);

            if (valid) {
                uint4 st;
                int sdt;
                if ((quad & 1) == 0) { st.x = p0x; st.y = p0y; st.z = q0x; st.w = q0y; sdt = dt; }
                else                 { st.x = q1x; st.y = q1y; st.z = p1x; st.w = p1y; sdt = dt + 1; }
                const int srow = (quad & 2) ? 8 : 0;
                *(uint4*)(prow + sdt * 16 + srow) = st;
            }
        }
    }
}

__global__ __launch_bounds__(256) void reduce_w(
    void* __restrict__ ws, float* __restrict__ out)
{
    const uint4* part4 = (const uint4*)((const char*)ws + PART_B);
    uint4* wbf4 = (uint4*)((char*)ws + WBF_B);
    const int gsz = NN * DD / 8;
    const int gid = blockIdx.x * 256 + threadIdx.x;

    const uint4 v0 = part4[gid];
    const uint4 v1 = part4[(long)gsz + gid];
    const uint4 v2 = part4[2L * gsz + gid];
    const uint4 v3 = part4[3L * gsz + gid];

    float s[8];
    s[0] = bf2f((ushort)v0.x) + bf2f((ushort)v1.x) + bf2f((ushort)v2.x) + bf2f((ushort)v3.x);
    s[1] = bf2f((ushort)(v0.x >> 16)) + bf2f((ushort)(v1.x >> 16)) + bf2f((ushort)(v2.x >> 16)) + bf2f((ushort)(v3.x >> 16));
    s[2] = bf2f((ushort)v0.y) + bf2f((ushort)v1.y) + bf2f((ushort)v2.y) + bf2f((ushort)v3.y);
    s[3] = bf2f((ushort)(v0.y >> 16)) + bf2f((ushort)(v1.y >> 16)) + bf2f((ushort)(v2.y >> 16)) + bf2f((ushort)(v3.y >> 16));
    s[4] = bf2f((ushort)v0.z) + bf2f((ushort)v1.z) + bf2f((ushort)v2.z) + bf2f((ushort)v3.z);
    s[5] = bf2f((ushort)(v0.z >> 16)) + bf2f((ushort)(v1.z >> 16)) + bf2f((ushort)(v2.z >> 16)) + bf2f((ushort)(v3.z >> 16));
    s[6] = bf2f((ushort)v0.w) + bf2f((ushort)v1.w) + bf2f((ushort)v2.w) + bf2f((ushort)v3.w);
    s[7] = bf2f((ushort)(v0.w >> 16)) + bf2f((ushort)(v1.w >> 16)) + bf2f((ushort)(v2.w >> 16)) + bf2f((ushort)(v3.w >> 16));

    float4* out4 = (float4*)out;
    out4[(long)gid * 2 + 0] = make_float4(s[0], s[1], s[2], s[3]);
    out4[(long)gid * 2 + 1] = make_float4(s[4], s[5], s[6], s[7]);

    uint4 pk;
    pk.x = (uint)f2bf(s[0]) | ((uint)f2bf(s[1]) << 16);
    pk.y = (uint)f2bf(s[2]) | ((uint)f2bf(s[3]) << 16);
    pk.z = (uint)f2bf(s[4]) | ((uint)f2bf(s[5]) << 16);
    pk.w = (uint)f2bf(s[6]) | ((uint)f2bf(s[7]) << 16);
    wbf4[gid] = pk;
}

__global__ __launch_bounds__(256) void pass_recon_mfma(
    const float* __restrict__ h_sparse, void* __restrict__ ws,
    float* __restrict__ out)
{
    const int e = blockIdx.x & 63, g = blockIdx.x >> 6;
    const int wave = threadIdx.x >> 6, lane = threadIdx.x & 63;
    const int quad = lane >> 4, l15 = lane & 15;
    const int t = threadIdx.x;

    const int* cnt = (const int*)ws;
    const ushort* bkt = (const ushort*)((const char*)ws + BKT_B);
    const ushort* Ute = (const ushort*)((const char*)ws + UT_B) + (long)e * BB * DD;
    const ushort* wbf = (const ushort*)((const char*)ws + WBF_B);

    __shared__ float loss_blk;
    if (t == 0) loss_blk = 0.f;
    __syncthreads();

    const int c  = cnt[e];
    const int lo = (c * g) >> 3;
    const int hi = (c * (g + 1)) >> 3;

    float lsum = 0.f;
    for (int base = lo + wave * 16; base < hi; base += 64) {
        const int pidx = base + l15;
        const bool valid = pidx < hi;
        const int id = valid ? (int)bkt[e * CAP + pidx] : 0;
        const int n = id >> 2;
        const ushort* wrow = wbf + ((long)n << 9);

        f32x4 acc = {0.f, 0.f, 0.f, 0.f};
        #pragma unroll 4
        for (int kk = 0; kk < 16; ++kk) {
            const int doff = kk * 32 + quad * 8;
            const short8 afrag = *(const short8*)(wrow + doff);
            const short8 bfrag = *(const short8*)(Ute + (long)l15 * DD + doff);
            acc = __builtin_amdgcn_mfma_f32_16x16x32_bf16(afrag, bfrag, acc, 0, 0, 0);
        }
        #pragma unroll
        for (int r = 0; r < 4; ++r) {
            const int pr = base + quad * 4 + r;
            if (pr < hi) {
                const int id2 = (int)bkt[e * CAP + pr];
                const float h = h_sparse[(long)id2 * BB + l15];
                const float d = acc[r] - h;
                lsum += d * d;
            }
        }
    }
    #pragma unroll
    for (int off = 32; off > 0; off >>= 1) lsum += __shfl_xor(lsum, off, 64);
    if (lane == 0 && lsum != 0.f) atomicAdd(&loss_blk, lsum);
    __syncthreads();
    if (t == 0 && loss_blk != 0.f)
        atomicAdd(out + (long)NN * DD, loss_blk * (1.0f / ((float)NN * KK * BB)));
}

// ===========================================================================
// Fallback path B (round-1 proven): tiny workspace
// ===========================================================================
__global__ __launch_bounds__(256) void norm_kernel(
    const float* __restrict__ U, float* __restrict__ inv_norm,
    float* __restrict__ loss_slot)
{
    const int m = blockIdx.x;
    const int t = threadIdx.x;
    const float* Um = U + (long)m * DP1 * BB;
    float acc = 0.f;
    for (int idx = t; idx < DP1 * BB; idx += 256) {
        float v = Um[idx];
        acc += v * v;
    }
    __shared__ float s[256];
    s[t] = acc;
    __syncthreads();
    if (t < BB) {
        float tot = 0.f;
        #pragma unroll
        for (int j = 0; j < 16; ++j) tot += s[t + 16 * j];
        inv_norm[m * BB + t] = rsqrtf(tot);
    }
    if (m == 0 && t == 0) *loss_slot = 0.f;
}

__global__ __launch_bounds__(256) void dense_write_kernel(
    const float* __restrict__ h_sparse,
    const int*   __restrict__ topk,
    const float* __restrict__ U,
    const float* __restrict__ inv_norm,
    float* __restrict__ out)
{
    const int n = blockIdx.x;
    const int t = threadIdx.x;

    __shared__ float hs[KK * BB];
    __shared__ float ho[KK * BB];
    __shared__ float inv_s[KK * BB];
    __shared__ int   eidx[KK];
    __shared__ float w_s[DD];
    __shared__ float red[256];

    if (t < KK) eidx[t] = topk[n * KK + t];
    __syncthreads();
    if (t < KK * BB) {
        const int k = t / BB, b = t % BB;
        const float h  = h_sparse[(long)n * KK * BB + t];
        const float iv = inv_norm[eidx[k] * BB + b];
        ho[t]    = h;
        inv_s[t] = iv;
        hs[t]    = h * iv;
    }
    __syncthreads();

    #pragma unroll
    for (int dd = 0; dd < 2; ++dd) {
        const int d = t + dd * 256;
        float w = 0.f;
        #pragma unroll
        for (int k = 0; k < KK; ++k) {
            const float4* row = (const float4*)(U + ((long)eidx[k] * DP1 + d) * BB);
            #pragma unroll
            for (int q = 0; q < 4; ++q) {
                const float4 u4 = row[q];
                w += u4.x * hs[k * BB + 4 * q + 0];
                w += u4.y * hs[k * BB + 4 * q + 1];
                w += u4.z * hs[k * BB + 4 * q + 2];
                w += u4.w * hs[k * BB + 4 * q + 3];
            }
        }
        w_s[d] = w;
        out[(long)n * DD + d] = w;
    }
    __syncthreads();

    {
        const int pair = t & 63;
        const int k = pair >> 4, b = pair & 15;
        const int ch = t >> 6;
        const float* Ucol = U + (long)eidx[k] * DP1 * BB + b;
        float p = 0.f;
        #pragma unroll 8
        for (int d = ch * 128; d < ch * 128 + 128; ++d) {
            p += Ucol[(long)d * BB] * w_s[d];
        }
        red[t] = p;
    }
    __syncthreads();

    if (t < 64) {
        const float recon = (red[t] + red[t + 64] + red[t + 128] + red[t + 192]) * inv_s[t];
        const float diff  = recon - ho[t];
        float sq = diff * diff;
        #pragma unroll
        for (int off = 32; off > 0; off >>= 1) sq += __shfl_down(sq, off, 64);
        if (t == 0) {
            atomicAdd(out + (long)NN * DD, sq * (1.0f / ((float)NN * KK * BB)));
        }
    }
}

// ===========================================================================

extern "C" void kernel_launch(void* const* d_in, const int* in_sizes, int n_in,
                              void* d_out, int out_size, void* d_ws, size_t ws_size,
                              hipStream_t stream) {
    const float* h_sparse = (const float*)d_in[0];
    const int*   topk     = (const int*)d_in[1];
    const float* U        = (const float*)d_in[2];
    float* out = (float*)d_out;
    void* ws = d_ws;

    if (ws_size >= (size_t)WS_NEED) {
        void* params[5] = { (void*)&h_sparse, (void*)&topk, (void*)&U,
                            (void*)&ws, (void*)&out };
        hipError_t err = hipLaunchCooperativeKernel(
            fused_all, dim3(GRID_C), dim3(256), params, 0, stream);
        if (err != hipSuccess) {
            // deterministic fallback: proven multi-kernel path
            hipLaunchKernelGGL(prep_kernel, dim3(MM), dim3(256), 0, stream,
                               U, ws, out + (long)NN * DD);
            hipLaunchKernelGGL(build_buckets, dim3(NPAIR / 256), dim3(256), 0, stream,
                               topk, ws);
            hipLaunchKernelGGL(pass_writes_mfma, dim3(MM * 8), dim3(256), 0, stream,
                               h_sparse, ws);
            hipLaunchKernelGGL(reduce_w, dim3(NN * DD / 8 / 256), dim3(256), 0, stream,
                               ws, out);
            hipLaunchKernelGGL(pass_recon_mfma, dim3(MM * 8), dim3(256), 0, stream,
                               h_sparse, ws, out);
        }
    } else {
        float* inv_norm = (float*)d_ws;
        hipLaunchKernelGGL(norm_kernel, dim3(MM), dim3(256), 0, stream,
                           U, inv_norm, out + (long)NN * DD);
        hipLaunchKernelGGL(dense_write_kernel, dim3(NN), dim3(256), 0, stream,
                           h_sparse, topk, U, inv_norm, out);
    }
}

// Round 8
// 126.518 us; speedup vs baseline: 3.3172x; 3.3172x over previous
//
#include <hip/hip_runtime.h>

#define DD 512
#define MM 64
#define BB 16
#define NN 8192
#define KK 4
#define DP1 513
#define CAP 1024
#define NPAIR (NN * KK)

// ws byte offsets
#define CNT_B  0                      // 64 int expert counts (256 B)
#define BKT_B  33024                  // 64*1024 ushort pair ids (128 KB)
#define U_B    164096                 // bf16 u[m][d][b], 1 MB
#define UT_B   1212672                // bf16 ut[m][b][d], 1 MB
#define WBF_B  2261248                // bf16 w[n][d], 8 MB
#define PART_B 10649856               // bf16 part[k][n][d], 32 MB
#define WS_NEED 44204288

typedef unsigned int uint;
typedef unsigned short ushort;
typedef __attribute__((ext_vector_type(8))) short short8;
typedef __attribute__((ext_vector_type(4))) float f32x4;

__device__ __forceinline__ ushort f2bf(float f) {
    uint u = __builtin_bit_cast(uint, f);
    uint r = (u + 0x7FFFu + ((u >> 16) & 1u)) >> 16;
    return (ushort)r;
}
__device__ __forceinline__ float bf2f(ushort s) {
    return __builtin_bit_cast(float, (uint)s << 16);
}

// ---------------------------------------------------------------------------
// K1 prep_build: blocks 0-255 = prep (4 blocks/expert, d-slice of 128);
//                blocks 256-383 = counting sort (independent, concurrent).
// cnt[] must be zeroed before this kernel (memset).
// ---------------------------------------------------------------------------
__global__ __launch_bounds__(256) void prep_build(
    const float* __restrict__ U,
    const int*   __restrict__ topk,
    void* __restrict__ ws,
    float* __restrict__ loss_slot)
{
    const int blk = blockIdx.x, t = threadIdx.x;

    if (blk < 256) {
        // ---- prep: expert m, d-slice sl ----
        const int m = blk >> 2, sl = blk & 3;
        const float* Um = U + (long)m * DP1 * BB;

        __shared__ float red[256];
        __shared__ float inv_s[BB];
        __shared__ ushort tr[BB][136];

        float a = 0.f;
        for (int i = t; i < DP1 * BB; i += 256) { float v = Um[i]; a += v * v; }
        red[t] = a;
        __syncthreads();
        if (t < BB) {
            float tot = 0.f;
            #pragma unroll
            for (int j = 0; j < 16; ++j) tot += red[t + 16 * j];
            inv_s[t] = rsqrtf(tot);
        }
        __syncthreads();

        ushort* ub = (ushort*)((char*)ws + U_B) + (long)m * DD * BB + sl * 2048;
        ushort* ut = (ushort*)((char*)ws + UT_B) + (long)m * BB * DD + sl * 128;
        const float* Us = Um + sl * 2048;

        #pragma unroll
        for (int iter = 0; iter < 4; ++iter) {
            const int i = t + iter * 256;      // 0..1023 element pairs
            const int e0 = 2 * i;              // 0..2046
            const int dl = e0 >> 4, b0 = e0 & 15;
            const float2 v = *(const float2*)(Us + e0);
            const ushort bv0 = f2bf(v.x * inv_s[b0]);
            const ushort bv1 = f2bf(v.y * inv_s[b0 + 1]);
            *(uint*)(ub + e0) = (uint)bv0 | ((uint)bv1 << 16);
            tr[b0][dl]     = bv0;
            tr[b0 + 1][dl] = bv1;
        }
        __syncthreads();
        {
            const int b = t >> 4, doff = (t & 15) * 8;
            uint4 val;
            val.x = (uint)tr[b][doff + 0] | ((uint)tr[b][doff + 1] << 16);
            val.y = (uint)tr[b][doff + 2] | ((uint)tr[b][doff + 3] << 16);
            val.z = (uint)tr[b][doff + 4] | ((uint)tr[b][doff + 5] << 16);
            val.w = (uint)tr[b][doff + 6] | ((uint)tr[b][doff + 7] << 16);
            *(uint4*)(ut + (long)b * DD + doff) = val;
        }
    } else {
        // ---- build: counting sort chunk (blk-256) ----
        const int cblk = blk - 256;
        int* cnt = (int*)ws;
        ushort* bkt = (ushort*)((char*)ws + BKT_B);
        __shared__ int lc[MM], lb[MM];
        if (t < MM) lc[t] = 0;
        __syncthreads();
        const int p = cblk * 256 + t;
        const int e = topk[p];
        const int my = atomicAdd(&lc[e], 1);
        __syncthreads();
        if (t < MM) lb[t] = atomicAdd(&cnt[t], lc[t]);
        __syncthreads();
        bkt[e * CAP + lb[e] + my] = (ushort)p;
        if (cblk == 0 && t == 0) *loss_slot = 0.f;
    }
}

// ---------------------------------------------------------------------------
// K2 (MFMA): part[k][n][d] = Un_e * h^T per 16-pair tile (K=16 padded to 32).
// e = blk & 63: all 8 slices of an expert land on one XCD (L2 locality).
// ---------------------------------------------------------------------------
__global__ __launch_bounds__(256) void pass_writes_mfma(
    const float* __restrict__ h_sparse, void* __restrict__ ws)
{
    const int e = blockIdx.x & 63, g = blockIdx.x >> 6;
    const int wave = threadIdx.x >> 6, lane = threadIdx.x & 63;
    const int quad = lane >> 4, l15 = lane & 15;

    const int* cnt = (const int*)ws;
    const ushort* bkt = (const ushort*)((const char*)ws + BKT_B);
    const ushort* Ue = (const ushort*)((const char*)ws + U_B) + (long)e * DD * BB;
    ushort* part = (ushort*)((char*)ws + PART_B);

    const int c  = cnt[e];
    const int lo = (c * g) >> 3;
    const int hi = (c * (g + 1)) >> 3;

    for (int base = lo + wave * 16; base < hi; base += 64) {
        const int pidx = base + l15;
        const bool valid = pidx < hi;
        const int id = valid ? (int)bkt[e * CAP + pidx] : 0;
        const int n = id >> 2, k = id & 3;

        short8 bfrag = (short8)0;
        if (quad < 2 && valid) {
            const float4* hp = (const float4*)(h_sparse + (long)id * BB + quad * 8);
            const float4 h0 = hp[0], h1 = hp[1];
            bfrag[0] = (short)f2bf(h0.x); bfrag[1] = (short)f2bf(h0.y);
            bfrag[2] = (short)f2bf(h0.z); bfrag[3] = (short)f2bf(h0.w);
            bfrag[4] = (short)f2bf(h1.x); bfrag[5] = (short)f2bf(h1.y);
            bfrag[6] = (short)f2bf(h1.z); bfrag[7] = (short)f2bf(h1.w);
        }
        ushort* prow = part + ((long)(k * NN + n) << 9);

        #pragma unroll 2
        for (int dt = 0; dt < 32; dt += 2) {
            short8 a0 = (short8)0, a1 = (short8)0;
            if (quad < 2) {
                a0 = *(const short8*)(Ue + ((long)(dt * 16 + l15) << 4) + quad * 8);
                a1 = *(const short8*)(Ue + ((long)((dt + 1) * 16 + l15) << 4) + quad * 8);
            }
            f32x4 z = {0.f, 0.f, 0.f, 0.f};
            f32x4 c0 = __builtin_amdgcn_mfma_f32_16x16x32_bf16(a0, bfrag, z, 0, 0, 0);
            f32x4 c1 = __builtin_amdgcn_mfma_f32_16x16x32_bf16(a1, bfrag, z, 0, 0, 0);

            uint p0x = (uint)f2bf(c0[0]) | ((uint)f2bf(c0[1]) << 16);
            uint p0y = (uint)f2bf(c0[2]) | ((uint)f2bf(c0[3]) << 16);
            uint p1x = (uint)f2bf(c1[0]) | ((uint)f2bf(c1[1]) << 16);
            uint p1y = (uint)f2bf(c1[2]) | ((uint)f2bf(c1[3]) << 16);
            uint q0x = __shfl_xor((int)p0x, 16, 64);
            uint q0y = __shfl_xor((int)p0y, 16, 64);
            uint q1x = __shfl_xor((int)p1x, 16, 64);
            uint q1y = __shfl_xor((int)p1y, 16, 64);

            if (valid) {
                uint4 st;
                int sdt;
                if ((quad & 1) == 0) { st.x = p0x; st.y = p0y; st.z = q0x; st.w = q0y; sdt = dt; }
                else                 { st.x = q1x; st.y = q1y; st.z = p1x; st.w = p1y; sdt = dt + 1; }
                const int srow = (quad & 2) ? 8 : 0;
                *(uint4*)(prow + sdt * 16 + srow) = st;
            }
        }
    }
}

// ---------------------------------------------------------------------------
// K3: w[n][d] = sum_k part[k][n][d]; write fp32 out + bf16 wbf (coalesced)
// ---------------------------------------------------------------------------
__global__ __launch_bounds__(256) void reduce_w(
    void* __restrict__ ws, float* __restrict__ out)
{
    const uint4* part4 = (const uint4*)((const char*)ws + PART_B);
    uint4* wbf4 = (uint4*)((char*)ws + WBF_B);
    const int gsz = NN * DD / 8;
    const int gid = blockIdx.x * 256 + threadIdx.x;

    const uint4 v0 = part4[gid];
    const uint4 v1 = part4[(long)gsz + gid];
    const uint4 v2 = part4[2L * gsz + gid];
    const uint4 v3 = part4[3L * gsz + gid];

    float s[8];
    s[0] = bf2f((ushort)v0.x) + bf2f((ushort)v1.x) + bf2f((ushort)v2.x) + bf2f((ushort)v3.x);
    s[1] = bf2f((ushort)(v0.x >> 16)) + bf2f((ushort)(v1.x >> 16)) + bf2f((ushort)(v2.x >> 16)) + bf2f((ushort)(v3.x >> 16));
    s[2] = bf2f((ushort)v0.y) + bf2f((ushort)v1.y) + bf2f((ushort)v2.y) + bf2f((ushort)v3.y);
    s[3] = bf2f((ushort)(v0.y >> 16)) + bf2f((ushort)(v1.y >> 16)) + bf2f((ushort)(v2.y >> 16)) + bf2f((ushort)(v3.y >> 16));
    s[4] = bf2f((ushort)v0.z) + bf2f((ushort)v1.z) + bf2f((ushort)v2.z) + bf2f((ushort)v3.z);
    s[5] = bf2f((ushort)(v0.z >> 16)) + bf2f((ushort)(v1.z >> 16)) + bf2f((ushort)(v2.z >> 16)) + bf2f((ushort)(v3.z >> 16));
    s[6] = bf2f((ushort)v0.w) + bf2f((ushort)v1.w) + bf2f((ushort)v2.w) + bf2f((ushort)v3.w);
    s[7] = bf2f((ushort)(v0.w >> 16)) + bf2f((ushort)(v1.w >> 16)) + bf2f((ushort)(v2.w >> 16)) + bf2f((ushort)(v3.w >> 16));

    float4* out4 = (float4*)out;
    out4[(long)gid * 2 + 0] = make_float4(s[0], s[1], s[2], s[3]);
    out4[(long)gid * 2 + 1] = make_float4(s[4], s[5], s[6], s[7]);

    uint4 pk;
    pk.x = (uint)f2bf(s[0]) | ((uint)f2bf(s[1]) << 16);
    pk.y = (uint)f2bf(s[2]) | ((uint)f2bf(s[3]) << 16);
    pk.z = (uint)f2bf(s[4]) | ((uint)f2bf(s[5]) << 16);
    pk.w = (uint)f2bf(s[6]) | ((uint)f2bf(s[7]) << 16);
    wbf4[gid] = pk;
}

// ---------------------------------------------------------------------------
// K4 (MFMA): recon[pair][b] = sum_d w[n][d]*Un[d][b]; loss only.
// e = blk & 63 (XCD locality, same as K2).
// ---------------------------------------------------------------------------
__global__ __launch_bounds__(256) void pass_recon_mfma(
    const float* __restrict__ h_sparse, void* __restrict__ ws,
    float* __restrict__ out)
{
    const int e = blockIdx.x & 63, g = blockIdx.x >> 6;
    const int wave = threadIdx.x >> 6, lane = threadIdx.x & 63;
    const int quad = lane >> 4, l15 = lane & 15;
    const int t = threadIdx.x;

    const int* cnt = (const int*)ws;
    const ushort* bkt = (const ushort*)((const char*)ws + BKT_B);
    const ushort* Ute = (const ushort*)((const char*)ws + UT_B) + (long)e * BB * DD;
    const ushort* wbf = (const ushort*)((const char*)ws + WBF_B);

    __shared__ float loss_blk;
    if (t == 0) loss_blk = 0.f;
    __syncthreads();

    const int c  = cnt[e];
    const int lo = (c * g) >> 3;
    const int hi = (c * (g + 1)) >> 3;

    float lsum = 0.f;
    for (int base = lo + wave * 16; base < hi; base += 64) {
        const int pidx = base + l15;
        const bool valid = pidx < hi;
        const int id = valid ? (int)bkt[e * CAP + pidx] : 0;
        const int n = id >> 2;
        const ushort* wrow = wbf + ((long)n << 9);

        f32x4 acc = {0.f, 0.f, 0.f, 0.f};
        #pragma unroll 4
        for (int kk = 0; kk < 16; ++kk) {
            const int doff = kk * 32 + quad * 8;
            const short8 afrag = *(const short8*)(wrow + doff);
            const short8 bfrag = *(const short8*)(Ute + (long)l15 * DD + doff);
            acc = __builtin_amdgcn_mfma_f32_16x16x32_bf16(afrag, bfrag, acc, 0, 0, 0);
        }
        #pragma unroll
        for (int r = 0; r < 4; ++r) {
            const int pr = base + quad * 4 + r;
            if (pr < hi) {
                const int id2 = (int)bkt[e * CAP + pr];
                const float h = h_sparse[(long)id2 * BB + l15];
                const float d = acc[r] - h;
                lsum += d * d;
            }
        }
    }
    #pragma unroll
    for (int off = 32; off > 0; off >>= 1) lsum += __shfl_xor(lsum, off, 64);
    if (lane == 0 && lsum != 0.f) atomicAdd(&loss_blk, lsum);
    __syncthreads();
    if (t == 0 && loss_blk != 0.f)
        atomicAdd(out + (long)NN * DD, loss_blk * (1.0f / ((float)NN * KK * BB)));
}

// ---------------------------------------------------------------------------
// Fallback (round-1 proven): tiny workspace
// ---------------------------------------------------------------------------
__global__ __launch_bounds__(256) void norm_kernel(
    const float* __restrict__ U, float* __restrict__ inv_norm,
    float* __restrict__ loss_slot)
{
    const int m = blockIdx.x;
    const int t = threadIdx.x;
    const float* Um = U + (long)m * DP1 * BB;
    float acc = 0.f;
    for (int idx = t; idx < DP1 * BB; idx += 256) {
        float v = Um[idx];
        acc += v * v;
    }
    __shared__ float s[256];
    s[t] = acc;
    __syncthreads();
    if (t < BB) {
        float tot = 0.f;
        #pragma unroll
        for (int j = 0; j < 16; ++j) tot += s[t + 16 * j];
        inv_norm[m * BB + t] = rsqrtf(tot);
    }
    if (m == 0 && t == 0) *loss_slot = 0.f;
}

__global__ __launch_bounds__(256) void dense_write_kernel(
    const float* __restrict__ h_sparse,
    const int*   __restrict__ topk,
    const float* __restrict__ U,
    const float* __restrict__ inv_norm,
    float* __restrict__ out)
{
    const int n = blockIdx.x;
    const int t = threadIdx.x;

    __shared__ float hs[KK * BB];
    __shared__ float ho[KK * BB];
    __shared__ float inv_s[KK * BB];
    __shared__ int   eidx[KK];
    __shared__ float w_s[DD];
    __shared__ float red[256];

    if (t < KK) eidx[t] = topk[n * KK + t];
    __syncthreads();
    if (t < KK * BB) {
        const int k = t / BB, b = t % BB;
        const float h  = h_sparse[(long)n * KK * BB + t];
        const float iv = inv_norm[eidx[k] * BB + b];
        ho[t]    = h;
        inv_s[t] = iv;
        hs[t]    = h * iv;
    }
    __syncthreads();

    #pragma unroll
    for (int dd = 0; dd < 2; ++dd) {
        const int d = t + dd * 256;
        float w = 0.f;
        #pragma unroll
        for (int k = 0; k < KK; ++k) {
            const float4* row = (const float4*)(U + ((long)eidx[k] * DP1 + d) * BB);
            #pragma unroll
            for (int q = 0; q < 4; ++q) {
                const float4 u4 = row[q];
                w += u4.x * hs[k * BB + 4 * q + 0];
                w += u4.y * hs[k * BB + 4 * q + 1];
                w += u4.z * hs[k * BB + 4 * q + 2];
                w += u4.w * hs[k * BB + 4 * q + 3];
            }
        }
        w_s[d] = w;
        out[(long)n * DD + d] = w;
    }
    __syncthreads();

    {
        const int pair = t & 63;
        const int k = pair >> 4, b = pair & 15;
        const int ch = t >> 6;
        const float* Ucol = U + (long)eidx[k] * DP1 * BB + b;
        float p = 0.f;
        #pragma unroll 8
        for (int d = ch * 128; d < ch * 128 + 128; ++d) {
            p += Ucol[(long)d * BB] * w_s[d];
        }
        red[t] = p;
    }
    __syncthreads();

    if (t < 64) {
        const float recon = (red[t] + red[t + 64] + red[t + 128] + red[t + 192]) * inv_s[t];
        const float diff  = recon - ho[t];
        float sq = diff * diff;
        #pragma unroll
        for (int off = 32; off > 0; off >>= 1) sq += __shfl_down(sq, off, 64);
        if (t == 0) {
            atomicAdd(out + (long)NN * DD, sq * (1.0f / ((float)NN * KK * BB)));
        }
    }
}

// ---------------------------------------------------------------------------

extern "C" void kernel_launch(void* const* d_in, const int* in_sizes, int n_in,
                              void* d_out, int out_size, void* d_ws, size_t ws_size,
                              hipStream_t stream) {
    const float* h_sparse = (const float*)d_in[0];
    const int*   topk     = (const int*)d_in[1];
    const float* U        = (const float*)d_in[2];
    float* out = (float*)d_out;

    if (ws_size >= (size_t)WS_NEED) {
        hipMemsetAsync(d_ws, 0, 256, stream);   // expert counters
        hipLaunchKernelGGL(prep_build, dim3(256 + NPAIR / 256), dim3(256), 0, stream,
                           U, topk, d_ws, out + (long)NN * DD);
        hipLaunchKernelGGL(pass_writes_mfma, dim3(MM * 8), dim3(256), 0, stream,
                           h_sparse, d_ws);
        hipLaunchKernelGGL(reduce_w, dim3(NN * DD / 8 / 256), dim3(256), 0, stream,
                           d_ws, out);
        hipLaunchKernelGGL(pass_recon_mfma, dim3(MM * 8), dim3(256), 0, stream,
                           h_sparse, d_ws, out);
    } else {
        float* inv_norm = (float*)d_ws;
        hipLaunchKernelGGL(norm_kernel, dim3(MM), dim3(256), 0, stream,
                           U, inv_norm, out + (long)NN * DD);
        hipLaunchKernelGGL(dense_write_kernel, dim3(NN), dim3(256), 0, stream,
                           h_sparse, topk, U, inv_norm, out);
    }
}